// Round 11
// baseline (133.917 us; speedup 1.0000x reference)
//
#include <hip/hip_runtime.h>

// out[N,32] = segment_sum(edge_val[e] * weight[edge_col[e], :], edge_row[e]) + bias
//
// v10: revert to v8's fused 3-kernel structure (best: 122us), plus:
//   - NON-TEMPORAL loads/stores for all single-use streams (edge arrays, parts
//     records, out stores): keeps the 4MB/XCD L2 for the weight gather (12.8MB
//     footprint), whose random-line misses to LLC are the measured ~3TB/s wall.
//   - part at 512 threads / EPT=8 (same 48KB LDS) -> 3 WGs/CU (was 2): better
//     cross-WG overlap of hist/scan/scatter/writeout phases.
//   K0 gnn_zero : cursor[B]=0, scnt=0
//   K1 gnn_part : per 4096-edge chunk (512 thr): nt vector edge loads, fused
//                 hist+slot, 2-per-thread two-level shfl scan, global run
//                 reservation, LDS bucket-order scatter (no atomics), coalesced
//                 nt writeout; overflow -> exact spill.
//   K2 gnn_accum: per bucket (512 thr): nt parts load to regs, fused row
//                 hist+slot, wave scan, LDS row-sort scatter (no atomics),
//                 64 groups x 8 lanes register gather (weight loads CACHED,
//                 8 float4 lines in flight), spill merge, nt coalesced
//                 store (+bias).
//
// Fallbacks: v2 bin+gather if ws too small / shape out of range; v0 atomics last.

#define FEAT 32
#define LOG_RPB 7
#define RPB (1 << LOG_RPB)
#define COLBITS 17
#define CMASK ((1u << COLBITS) - 1)
#define BMAX 1024
#define PCHUNK 4096
#define PTHREADS 512
#define EPT (PCHUNK / PTHREADS)      // 8 edges per thread
#define CAPB 2560                    // record slots per bucket (mult of 512)
#define CAP_MAX 32

typedef float  nf4 __attribute__((ext_vector_type(4)));
typedef float  nf2 __attribute__((ext_vector_type(2)));
typedef int    ni4 __attribute__((ext_vector_type(4)));

__device__ __forceinline__ float4 nt_load_f4(const float* p) {
    nf4 v = __builtin_nontemporal_load((const nf4*)p);
    return make_float4(v.x, v.y, v.z, v.w);
}
__device__ __forceinline__ float2 nt_load_f2(const float2* p) {
    nf2 v = __builtin_nontemporal_load((const nf2*)p);
    return make_float2(v.x, v.y);
}
__device__ __forceinline__ void nt_store_f2(float2* p, float2 v) {
    nf2 x; x.x = v.x; x.y = v.y;
    __builtin_nontemporal_store(x, (nf2*)p);
}
__device__ __forceinline__ void nt_store_f4(float* p, float4 v) {
    nf4 x; x.x = v.x; x.y = v.y; x.z = v.z; x.w = v.w;
    __builtin_nontemporal_store(x, (nf4*)p);
}

// ---------------- v10 kernels ----------------

__global__ __launch_bounds__(256) void gnn_zero(
    int* __restrict__ cursor, int* __restrict__ scnt, int B) {
    int i = blockIdx.x * 256 + threadIdx.x;
    if (i < B) cursor[i] = 0;
    if (i == B) *scnt = 0;
}

__global__ __launch_bounds__(PTHREADS) void gnn_part(
    const int* __restrict__ edge_row,
    const int* __restrict__ edge_col,
    const float* __restrict__ edge_val,
    int* __restrict__ cursor,
    float2* __restrict__ parts,
    float4* __restrict__ spill,
    int* __restrict__ scnt,
    int num_edges, int B) {
    __shared__ float2 lrec[PCHUNK];              // 32 KB
    __shared__ unsigned short lbkt[PCHUNK];      // 8 KB
    __shared__ int hcur[BMAX];                   // hist+slots, then run base
    __shared__ int st[BMAX];                     // exclusive starts
    __shared__ int wtot[8], wbase[8];
    int t = threadIdx.x;
    for (int b = t; b < BMAX; b += PTHREADS) hcur[b] = 0;
    __syncthreads();

    int e0 = blockIdx.x * PCHUNK;
    int cnt_chunk = num_edges - e0;
    if (cnt_chunk > PCHUNK) cnt_chunk = PCHUNK;

    // 1) nt vectorized edge loads (8 consecutive edges/thread) + fused hist/slot
    int  r[EPT], c[EPT], bb[EPT], slot[EPT];
    float vv[EPT];
    int ebase = e0 + EPT * t;
    if (ebase + EPT - 1 < num_edges) {
        ni4 r0 = __builtin_nontemporal_load((const ni4*)(edge_row + ebase));
        ni4 r1 = __builtin_nontemporal_load((const ni4*)(edge_row + ebase + 4));
        ni4 c0 = __builtin_nontemporal_load((const ni4*)(edge_col + ebase));
        ni4 c1 = __builtin_nontemporal_load((const ni4*)(edge_col + ebase + 4));
        nf4 v0 = __builtin_nontemporal_load((const nf4*)(edge_val + ebase));
        nf4 v1 = __builtin_nontemporal_load((const nf4*)(edge_val + ebase + 4));
        r[0]=r0.x; r[1]=r0.y; r[2]=r0.z; r[3]=r0.w;
        r[4]=r1.x; r[5]=r1.y; r[6]=r1.z; r[7]=r1.w;
        c[0]=c0.x; c[1]=c0.y; c[2]=c0.z; c[3]=c0.w;
        c[4]=c1.x; c[5]=c1.y; c[6]=c1.z; c[7]=c1.w;
        vv[0]=v0.x; vv[1]=v0.y; vv[2]=v0.z; vv[3]=v0.w;
        vv[4]=v1.x; vv[5]=v1.y; vv[6]=v1.z; vv[7]=v1.w;
    } else {
        #pragma unroll
        for (int k = 0; k < EPT; ++k) {
            int e = ebase + k;
            bool ok = e < num_edges;
            r[k]  = ok ? edge_row[e] : -1;
            c[k]  = ok ? edge_col[e] : 0;
            vv[k] = ok ? edge_val[e] : 0.f;
        }
    }
    #pragma unroll
    for (int k = 0; k < EPT; ++k) {
        if (r[k] >= 0) {
            bb[k] = r[k] >> LOG_RPB;
            slot[k] = atomicAdd(&hcur[bb[k]], 1);   // rank within bucket
        }
    }
    __syncthreads();

    // 2) scan of 1024 counts, 2 buckets/thread, two-level shfl (3 barriers)
    int a  = hcur[2 * t];
    int b2 = hcur[2 * t + 1];
    int pr = a + b2;
    int lane = t & 63, wid = t >> 6;             // 8 waves
    int x = pr;
    #pragma unroll
    for (int off = 1; off < 64; off <<= 1) {
        int y = __shfl_up(x, off);
        if (lane >= off) x += y;
    }
    if (lane == 63) wtot[wid] = x;
    __syncthreads();
    if (t < 8) {
        int w = wtot[t], xx = w;
        #pragma unroll
        for (int off = 1; off < 8; off <<= 1) {
            int y = __shfl_up(xx, off);
            if (t >= off) xx += y;
        }
        wbase[t] = xx - w;
    }
    __syncthreads();
    int ex = x - pr + wbase[wid];                // exclusive start of bucket 2t
    st[2 * t]     = ex;
    st[2 * t + 1] = ex + a;
    int rb0 = (a  && 2 * t     < B) ? atomicAdd(&cursor[2 * t],     a)  : 0;
    int rb1 = (b2 && 2 * t + 1 < B) ? atomicAdd(&cursor[2 * t + 1], b2) : 0;
    __syncthreads();                             // all reads of hcur done
    hcur[2 * t]     = rb0;                       // reuse as global run base
    hcur[2 * t + 1] = rb1;
    __syncthreads();

    // 3) scatter into LDS in bucket order — NO atomics (slot known)
    #pragma unroll
    for (int k = 0; k < EPT; ++k) {
        if (r[k] >= 0) {
            int pos = st[bb[k]] + slot[k];
            unsigned pk = (unsigned)c[k] |
                          ((unsigned)(r[k] & (RPB - 1)) << COLBITS);
            lrec[pos] = make_float2(__uint_as_float(pk), vv[k]);
            lbkt[pos] = (unsigned short)bb[k];
        }
    }
    __syncthreads();

    // 4) coalesced nt writeout (consecutive i -> consecutive slots of a bucket)
    for (int i = t; i < cnt_chunk; i += PTHREADS) {
        int b3 = lbkt[i];
        float2 rec = lrec[i];
        int s = hcur[b3] + (i - st[b3]);
        if (s < CAPB) {
            nt_store_f2(&parts[(long long)b3 * CAPB + s], rec);
        } else {
            // exact overflow path (never taken for uniform data)
            int si = atomicAdd(scnt, 1);
            unsigned pk = __float_as_uint(rec.x);
            spill[si] = make_float4(
                __uint_as_float((unsigned)(b3 << LOG_RPB) + (pk >> COLBITS)),
                __uint_as_float(pk & CMASK), rec.y, 0.f);
        }
    }
}

__global__ __launch_bounds__(512) void gnn_accum(
    const float2* __restrict__ parts,
    const int* __restrict__ cursor,
    const int* __restrict__ scnt,
    const float4* __restrict__ spill,
    const float* __restrict__ weight,
    const float* __restrict__ bias,
    float* __restrict__ out,
    int n_nodes) {
    __shared__ float2 srec[CAPB];       // 20 KB: row-sorted records
    __shared__ int h[RPB];
    __shared__ int rs[RPB + 1];
    int b = blockIdx.x, t = threadIdx.x;
    int n = cursor[b];
    int nspill = *scnt;                 // uniform; 0 in the common case
    int m = n < CAPB ? n : CAPB;
    const float2* p = parts + (long long)b * CAPB;

    // 1) nt load records to registers + fused row histogram/slot
    float2 rec[CAPB / 512];
    int rl[CAPB / 512], slot[CAPB / 512];
    if (t < RPB) h[t] = 0;
    __syncthreads();
    #pragma unroll
    for (int k = 0; k < CAPB / 512; ++k) {
        int idx = t + k * 512;
        bool ok = idx < m;
        rec[k] = ok ? nt_load_f2(&p[idx]) : make_float2(0.f, 0.f);
        if (ok) {
            rl[k] = (int)((__float_as_uint(rec[k].x) >> COLBITS) & (RPB - 1));
            slot[k] = atomicAdd(&h[rl[k]], 1);     // rank within row
        }
    }
    __syncthreads();

    // 2) wave-0 scan of 128 row counts via shfl (2 elems/lane)
    if (t < 64) {
        int a  = h[2 * t];
        int c2 = h[2 * t + 1];
        int pr = a + c2;
        int x = pr;
        #pragma unroll
        for (int off = 1; off < 64; off <<= 1) {
            int y = __shfl_up(x, off);
            if (t >= off) x += y;
        }
        int exc = x - pr;
        rs[2 * t] = exc;
        rs[2 * t + 1] = exc + a;
        if (t == 63) rs[RPB] = x;
    }
    __syncthreads();

    // 3) scatter registers -> row-sorted LDS — NO atomics
    #pragma unroll
    for (int k = 0; k < CAPB / 512; ++k) {
        int idx = t + k * 512;
        if (idx < m) srec[rs[rl[k]] + slot[k]] = rec[k];
    }
    __syncthreads();

    // 4) register-accumulate gather: 64 groups of 8 lanes; group owns 2 rows.
    //    Weight loads are CACHED (L2 kept clean by nt on the streams).
    int g = t >> 3;                     // 64 groups
    int l = t & 7;
    int row0 = b << LOG_RPB;
    float4 bf4 = ((const float4*)bias)[l];
    #pragma unroll 1
    for (int rr = 0; rr < 2; ++rr) {
        int rlc = (g << 1) + rr;
        int s = rs[rlc], e = rs[rlc + 1];
        float4 acc = make_float4(0.f, 0.f, 0.f, 0.f);
        for (int j = s; j < e; j += 8) {
            unsigned pk[8]; float vvv[8];
            #pragma unroll
            for (int k = 0; k < 8; ++k) {
                int jj = j + k;
                float2 rc = srec[jj < e ? jj : s];      // broadcast LDS read
                pk[k] = __float_as_uint(rc.x);
                vvv[k] = rc.y;
            }
            float4 w4[8];
            #pragma unroll
            for (int k = 0; k < 8; ++k)
                w4[k] = *(const float4*)(
                    weight + (long long)(pk[k] & CMASK) * FEAT + (l << 2));
            #pragma unroll
            for (int k = 0; k < 8; ++k) {
                float sc = (j + k < e) ? vvv[k] : 0.f;
                acc.x += sc * w4[k].x;
                acc.y += sc * w4[k].y;
                acc.z += sc * w4[k].z;
                acc.w += sc * w4[k].w;
            }
        }
        // merge rare spill entries for this row (nspill==0 normally)
        if (nspill > 0) {
            for (int i = 0; i < nspill; ++i) {
                float4 sp = spill[i];
                if ((int)__float_as_uint(sp.x) == row0 + rlc) {
                    const float4 wz = *(const float4*)(
                        weight + (long long)__float_as_uint(sp.y) * FEAT +
                        (l << 2));
                    acc.x += sp.z * wz.x;
                    acc.y += sp.z * wz.y;
                    acc.z += sp.z * wz.z;
                    acc.w += sp.z * wz.w;
                }
            }
        }
        int rrow = row0 + rlc;
        if (rrow < n_nodes) {
            float4 o = make_float4(acc.x + bf4.x, acc.y + bf4.y,
                                   acc.z + bf4.z, acc.w + bf4.w);
            nt_store_f4(out + (long long)rrow * FEAT + (l << 2), o);
        }
    }
}

// ---------------- v2 fallback (bin + gather) ----------------

__global__ __launch_bounds__(256) void gnn_init(
    const float* __restrict__ bias, float* __restrict__ out,
    int* __restrict__ cnt, int total4, int n_nodes) {
    int i = blockIdx.x * blockDim.x + threadIdx.x;
    if (i < total4) {
        float4 bb = ((const float4*)bias)[i & 7];
        ((float4*)out)[i] = bb;
    }
    if (i < n_nodes) cnt[i] = 0;
}

__global__ __launch_bounds__(256) void gnn_bin(
    const int* __restrict__ edge_row,
    const int* __restrict__ edge_col,
    const float* __restrict__ edge_val,
    const float* __restrict__ weight,
    float2* __restrict__ bins,
    int* __restrict__ cnt,
    float* __restrict__ out,
    int num_edges, int cap) {
    int e = blockIdx.x * blockDim.x + threadIdx.x;
    if (e >= num_edges) return;
    int r = edge_row[e];
    int c = edge_col[e];
    float v = edge_val[e];
    int slot = atomicAdd(&cnt[r], 1);
    if (slot < cap) {
        bins[(long long)r * cap + slot] = make_float2(__int_as_float(c), v);
    } else {
        const float* w = weight + (long long)c * FEAT;
        #pragma unroll
        for (int f = 0; f < FEAT; ++f)
            atomicAdd(out + (long long)r * FEAT + f, v * w[f]);
    }
}

__global__ __launch_bounds__(256) void gnn_gather(
    const float2* __restrict__ bins,
    const int* __restrict__ cnt,
    const float* __restrict__ weight,
    float* __restrict__ out,
    int n_nodes, int cap) {
    int g = (blockIdx.x * blockDim.x + threadIdx.x) >> 5;
    int f = threadIdx.x & (FEAT - 1);
    if (g >= n_nodes) return;
    int n = cnt[g];
    n = n < cap ? n : cap;
    const float2* b = bins + (long long)g * cap;
    float a0 = 0.f, a1 = 0.f, a2 = 0.f, a3 = 0.f;
    int j = 0;
    for (; j + 4 <= n; j += 4) {
        float2 e0 = b[j], e1 = b[j + 1], e2 = b[j + 2], e3 = b[j + 3];
        a0 += e0.y * weight[(long long)__float_as_int(e0.x) * FEAT + f];
        a1 += e1.y * weight[(long long)__float_as_int(e1.x) * FEAT + f];
        a2 += e2.y * weight[(long long)__float_as_int(e2.x) * FEAT + f];
        a3 += e3.y * weight[(long long)__float_as_int(e3.x) * FEAT + f];
    }
    for (; j < n; ++j) {
        float2 e0 = b[j];
        a0 += e0.y * weight[(long long)__float_as_int(e0.x) * FEAT + f];
    }
    out[(long long)g * FEAT + f] += (a0 + a1) + (a2 + a3);
}

// ---------------- v0 fallback ----------------

__global__ __launch_bounds__(256) void gnn_init_out(
    const float* __restrict__ bias, float* __restrict__ out, int total) {
    int i = blockIdx.x * blockDim.x + threadIdx.x;
    if (i < total) out[i] = bias[i & (FEAT - 1)];
}

__global__ __launch_bounds__(256) void gnn_scatter(
    const int* __restrict__ edge_row,
    const int* __restrict__ edge_col,
    const float* __restrict__ edge_val,
    const float* __restrict__ weight,
    float* __restrict__ out,
    int num_edges) {
    long long t = (long long)blockIdx.x * blockDim.x + threadIdx.x;
    int e = (int)(t >> 5);
    int f = (int)(t & (FEAT - 1));
    if (e < num_edges) {
        int r = edge_row[e];
        int c = edge_col[e];
        atomicAdd(out + r * FEAT + f, edge_val[e] * weight[c * FEAT + f]);
    }
}

extern "C" void kernel_launch(void* const* d_in, const int* in_sizes, int n_in,
                              void* d_out, int out_size, void* d_ws, size_t ws_size,
                              hipStream_t stream) {
    const int*   edge_row = (const int*)d_in[0];
    const int*   edge_col = (const int*)d_in[1];
    const float* edge_val = (const float*)d_in[2];
    const float* weight   = (const float*)d_in[3];
    const float* bias     = (const float*)d_in[4];
    float* out = (float*)d_out;

    const int E = in_sizes[0];
    const int total = out_size;        // N * 32 elements
    const int N = total / FEAT;
    const int B = (N + RPB - 1) >> LOG_RPB;

    auto align256 = [](size_t x) { return (x + 255) & ~(size_t)255; };
    size_t cursor_off = 0;
    size_t scnt_off   = align256(cursor_off + (size_t)B * sizeof(int));
    size_t spill_off  = align256(scnt_off + sizeof(int));
    size_t parts_off  = align256(spill_off + (size_t)E * sizeof(float4));
    size_t need_v10   = parts_off + (size_t)B * CAPB * sizeof(float2);

    if (B >= 1 && B <= BMAX && N <= (1 << COLBITS) && E > 0 && ws_size >= need_v10) {
        int*    cursor = (int*)((char*)d_ws + cursor_off);
        int*    scnt   = (int*)((char*)d_ws + scnt_off);
        float4* spill  = (float4*)((char*)d_ws + spill_off);
        float2* parts  = (float2*)((char*)d_ws + parts_off);

        gnn_zero<<<(B + 1 + 255) / 256, 256, 0, stream>>>(cursor, scnt, B);
        gnn_part<<<(E + PCHUNK - 1) / PCHUNK, PTHREADS, 0, stream>>>(
            edge_row, edge_col, edge_val, cursor, parts, spill, scnt, E, B);
        gnn_accum<<<B, 512, 0, stream>>>(
            parts, cursor, scnt, spill, weight, bias, out, N);
        return;
    }

    // v2 fallback: bin + gather
    size_t cnt_bytes = align256((size_t)N * sizeof(int));
    long long cap_ll = 0;
    if (ws_size > cnt_bytes)
        cap_ll = (long long)((ws_size - cnt_bytes) / ((size_t)N * sizeof(float2)));
    int cap = (int)(cap_ll > CAP_MAX ? CAP_MAX : cap_ll);

    if (cap >= 16) {
        int* cnt = (int*)d_ws;
        float2* bins = (float2*)((char*)d_ws + cnt_bytes);
        int total4 = total / 4;
        int init_threads = total4 > N ? total4 : N;
        gnn_init<<<(init_threads + 255) / 256, 256, 0, stream>>>(
            bias, out, cnt, total4, N);
        gnn_bin<<<(E + 255) / 256, 256, 0, stream>>>(
            edge_row, edge_col, edge_val, weight, bins, cnt, out, E, cap);
        long long gthreads = (long long)N * FEAT;
        gnn_gather<<<(int)((gthreads + 255) / 256), 256, 0, stream>>>(
            bins, cnt, weight, out, N, cap);
    } else {
        gnn_init_out<<<(total + 255) / 256, 256, 0, stream>>>(bias, out, total);
        long long threads = (long long)E * FEAT;
        gnn_scatter<<<(int)((threads + 255) / 256), 256, 0, stream>>>(
            edge_row, edge_col, edge_val, weight, out, E);
    }
}

// Round 12
// 126.280 us; speedup vs baseline: 1.0605x; 1.0605x over previous
//
#include <hip/hip_runtime.h>

// out[N,32] = segment_sum(edge_val[e] * weight[edge_col[e], :], edge_row[e]) + bias
//
// v11: TWO-LEVEL partition (long coalesced runs) + v8's fused accum.
//   Level A: 49 super-buckets (2048 rows). Per 4096-edge chunk, runs ~84 recs
//            (672B) -> ~1 store destination per wave.
//   Level B: per super-bucket 4096-rec chunk -> 16 fine buckets (128 rows),
//            runs ~256 recs (2KB) -> fully coalesced.
//   Accum:   per fine bucket (512 thr): regs load, fused row hist+slot, wave
//            scan, LDS row-sort, 64x8-lane register gather (8 float4 weight
//            lines in flight), spill merge, coalesced store (+bias).
//   All loads/stores CACHED (v10 showed NT on the parts round-trip regresses).
//   Exact spill list handles any bucket overflow (never taken for uniform).
//
// Fallbacks: v2 bin+gather if ws too small / shape out of range; v0 atomics last.

#define FEAT 32
#define LOG_RPB 7
#define RPB (1 << LOG_RPB)
#define COLBITS 17
#define CMASK ((1u << COLBITS) - 1)
#define LOG_SBR 11                   // 2048 rows per super-bucket
#define SBROWS (1 << LOG_SBR)
#define NSB_MAX 64
#define SBCAP 36864                  // 9*4096; mean 32768, +22 sigma
#define BCHUNKS 9                    // SBCAP / 4096
#define FPS (SBROWS / RPB)           // fine buckets per super-bucket = 16
#define BMAX 1024
#define PCHUNK 4096
#define PTHREADS 1024
#define EPT 4
#define CAPB 2560
#define CAP_MAX 32

// ---------------- v11 kernels ----------------

__global__ __launch_bounds__(256) void gnn_zero(int* __restrict__ p, int n) {
    int i = blockIdx.x * 256 + threadIdx.x;
    if (i < n) p[i] = 0;
}

// Level A: edges -> 49 super-buckets. Record: (col | row_in_sb<<17, val)
__global__ __launch_bounds__(PTHREADS) void gnn_parta(
    const int* __restrict__ edge_row,
    const int* __restrict__ edge_col,
    const float* __restrict__ edge_val,
    int* __restrict__ cursor_sb,
    float2* __restrict__ sbparts,
    float4* __restrict__ spill,
    int* __restrict__ scnt,
    int num_edges, int nsb) {
    __shared__ float2 lrec[PCHUNK];              // 32 KB
    __shared__ unsigned char lsb[PCHUNK];        // 4 KB
    __shared__ int hist[NSB_MAX];
    __shared__ int st[NSB_MAX];
    __shared__ int rb[NSB_MAX];
    int t = threadIdx.x;
    if (t < NSB_MAX) hist[t] = 0;
    __syncthreads();

    int e0 = blockIdx.x * PCHUNK;
    int cnt_chunk = num_edges - e0;
    if (cnt_chunk > PCHUNK) cnt_chunk = PCHUNK;

    // 1) vectorized edge loads + fused histogram/slot
    int r[EPT], c[EPT], sb[EPT], slot[EPT];
    float vv[EPT];
    int ebase = e0 + 4 * t;
    if (ebase + 3 < num_edges) {
        int4  r4 = *(const int4*)(edge_row + ebase);
        int4  c4 = *(const int4*)(edge_col + ebase);
        float4 v4 = *(const float4*)(edge_val + ebase);
        r[0]=r4.x; r[1]=r4.y; r[2]=r4.z; r[3]=r4.w;
        c[0]=c4.x; c[1]=c4.y; c[2]=c4.z; c[3]=c4.w;
        vv[0]=v4.x; vv[1]=v4.y; vv[2]=v4.z; vv[3]=v4.w;
    } else {
        #pragma unroll
        for (int k = 0; k < EPT; ++k) {
            int e = ebase + k;
            bool ok = e < num_edges;
            r[k]  = ok ? edge_row[e] : -1;
            c[k]  = ok ? edge_col[e] : 0;
            vv[k] = ok ? edge_val[e] : 0.f;
        }
    }
    #pragma unroll
    for (int k = 0; k < EPT; ++k) {
        if (r[k] >= 0) {
            sb[k] = r[k] >> LOG_SBR;
            slot[k] = atomicAdd(&hist[sb[k]], 1);
        }
    }
    __syncthreads();

    // 2) wave-0 scan over 64 super-bucket counts + global run reservation
    if (t < NSB_MAX) {
        int v = hist[t];
        int x = v;
        #pragma unroll
        for (int off = 1; off < 64; off <<= 1) {
            int y = __shfl_up(x, off);
            if (t >= off) x += y;
        }
        st[t] = x - v;
        rb[t] = (v && t < nsb) ? atomicAdd(&cursor_sb[t], v) : 0;
    }
    __syncthreads();

    // 3) scatter into LDS in super-bucket order (no atomics)
    #pragma unroll
    for (int k = 0; k < EPT; ++k) {
        if (r[k] >= 0) {
            int pos = st[sb[k]] + slot[k];
            unsigned pk = (unsigned)c[k] |
                          ((unsigned)(r[k] & (SBROWS - 1)) << COLBITS);
            lrec[pos] = make_float2(__uint_as_float(pk), vv[k]);
            lsb[pos] = (unsigned char)sb[k];
        }
    }
    __syncthreads();

    // 4) coalesced writeout: runs ~84 recs per super-bucket
    for (int i = t; i < cnt_chunk; i += PTHREADS) {
        int b2 = lsb[i];
        float2 rec = lrec[i];
        int s = rb[b2] + (i - st[b2]);
        if (s < SBCAP) {
            sbparts[(long long)b2 * SBCAP + s] = rec;
        } else {
            int si = atomicAdd(scnt, 1);
            unsigned pk = __float_as_uint(rec.x);
            spill[si] = make_float4(
                __uint_as_float((unsigned)(b2 << LOG_SBR) + (pk >> COLBITS)),
                __uint_as_float(pk & CMASK), rec.y, 0.f);
        }
    }
}

// Level B: super-bucket chunk -> 16 fine buckets. Rec: (col | row&127<<17, val)
__global__ __launch_bounds__(PTHREADS) void gnn_partb(
    const float2* __restrict__ sbparts,
    const int* __restrict__ cursor_sb,
    int* __restrict__ cursor_fine,
    float2* __restrict__ parts,
    float4* __restrict__ spill,
    int* __restrict__ scnt,
    int n_fine) {
    __shared__ float2 lrec[PCHUNK];              // 32 KB
    __shared__ unsigned char lfb[PCHUNK];        // 4 KB
    __shared__ int hist[FPS];
    __shared__ int st[FPS];
    __shared__ int rb[FPS];
    int t = threadIdx.x;
    int sb = blockIdx.x / BCHUNKS;
    int ch = blockIdx.x % BCHUNKS;
    int n_sb = cursor_sb[sb];
    if (n_sb > SBCAP) n_sb = SBCAP;
    int lo = ch * PCHUNK;
    int m = n_sb - lo;
    if (m <= 0) return;                          // uniform exit: idle chunk
    if (m > PCHUNK) m = PCHUNK;
    if (t < FPS) hist[t] = 0;
    __syncthreads();

    const float2* src = sbparts + (long long)sb * SBCAP + lo;

    // 1) vector record loads (4/thread) + fused fine histogram/slot
    float2 rec[EPT];
    int fb[EPT], slot[EPT];
    int rbase = 4 * t;
    if (rbase + 3 < m) {
        float4 q0 = *(const float4*)(src + rbase);
        float4 q1 = *(const float4*)(src + rbase + 2);
        rec[0] = make_float2(q0.x, q0.y);
        rec[1] = make_float2(q0.z, q0.w);
        rec[2] = make_float2(q1.x, q1.y);
        rec[3] = make_float2(q1.z, q1.w);
    } else {
        #pragma unroll
        for (int k = 0; k < EPT; ++k) {
            int idx = rbase + k;
            rec[k] = (idx < m) ? src[idx] : make_float2(__uint_as_float(~0u), 0.f);
        }
    }
    #pragma unroll
    for (int k = 0; k < EPT; ++k) {
        unsigned pk = __float_as_uint(rec[k].x);
        if (pk != ~0u) {
            fb[k] = (int)((pk >> COLBITS) >> LOG_RPB);   // 0..15
            slot[k] = atomicAdd(&hist[fb[k]], 1);
        } else fb[k] = -1;
    }
    __syncthreads();

    // 2) lanes 0..15 scan + global fine-cursor reservation
    if (t < FPS) {
        int v = hist[t];
        int x = v;
        #pragma unroll
        for (int off = 1; off < FPS; off <<= 1) {
            int y = __shfl_up(x, off);
            if (t >= off) x += y;
        }
        st[t] = x - v;
        int fg = sb * FPS + t;
        rb[t] = (v && fg < n_fine) ? atomicAdd(&cursor_fine[fg], v) : 0;
    }
    __syncthreads();

    // 3) scatter into LDS in fine-bucket order, rewriting to accum format
    #pragma unroll
    for (int k = 0; k < EPT; ++k) {
        if (fb[k] >= 0) {
            int pos = st[fb[k]] + slot[k];
            unsigned pk = __float_as_uint(rec[k].x);
            unsigned npk = pk & ((1u << (COLBITS + LOG_RPB)) - 1); // col|row&127
            lrec[pos] = make_float2(__uint_as_float(npk), rec[k].y);
            lfb[pos] = (unsigned char)fb[k];
        }
    }
    __syncthreads();

    // 4) coalesced writeout: runs ~256 recs (2KB) per fine bucket
    for (int i = t; i < m; i += PTHREADS) {
        int f2 = lfb[i];
        float2 rc = lrec[i];
        int fg = sb * FPS + f2;
        int s = rb[f2] + (i - st[f2]);
        if (s < CAPB) {
            parts[(long long)fg * CAPB + s] = rc;
        } else {
            int si = atomicAdd(scnt, 1);
            unsigned pk = __float_as_uint(rc.x);
            spill[si] = make_float4(
                __uint_as_float((unsigned)(fg << LOG_RPB) + (pk >> COLBITS)),
                __uint_as_float(pk & CMASK), rc.y, 0.f);
        }
    }
}

__global__ __launch_bounds__(512) void gnn_accum(
    const float2* __restrict__ parts,
    const int* __restrict__ cursor_fine,
    const int* __restrict__ scnt,
    const float4* __restrict__ spill,
    const float* __restrict__ weight,
    const float* __restrict__ bias,
    float* __restrict__ out,
    int n_nodes) {
    __shared__ float2 srec[CAPB];       // 20 KB
    __shared__ int h[RPB];
    __shared__ int rs[RPB + 1];
    int b = blockIdx.x, t = threadIdx.x;
    int n = cursor_fine[b];
    int nspill = *scnt;
    int m = n < CAPB ? n : CAPB;
    const float2* p = parts + (long long)b * CAPB;

    float2 rec[CAPB / 512];
    int rl[CAPB / 512], slot[CAPB / 512];
    if (t < RPB) h[t] = 0;
    __syncthreads();
    #pragma unroll
    for (int k = 0; k < CAPB / 512; ++k) {
        int idx = t + k * 512;
        bool ok = idx < m;
        rec[k] = ok ? p[idx] : make_float2(0.f, 0.f);
        if (ok) {
            rl[k] = (int)((__float_as_uint(rec[k].x) >> COLBITS) & (RPB - 1));
            slot[k] = atomicAdd(&h[rl[k]], 1);
        }
    }
    __syncthreads();

    if (t < 64) {
        int a  = h[2 * t];
        int c2 = h[2 * t + 1];
        int pr = a + c2;
        int x = pr;
        #pragma unroll
        for (int off = 1; off < 64; off <<= 1) {
            int y = __shfl_up(x, off);
            if (t >= off) x += y;
        }
        int exc = x - pr;
        rs[2 * t] = exc;
        rs[2 * t + 1] = exc + a;
        if (t == 63) rs[RPB] = x;
    }
    __syncthreads();

    #pragma unroll
    for (int k = 0; k < CAPB / 512; ++k) {
        int idx = t + k * 512;
        if (idx < m) srec[rs[rl[k]] + slot[k]] = rec[k];
    }
    __syncthreads();

    int g = t >> 3;                     // 64 groups of 8 lanes
    int l = t & 7;
    int row0 = b << LOG_RPB;
    float4 bf4 = ((const float4*)bias)[l];
    #pragma unroll 1
    for (int rr = 0; rr < 2; ++rr) {
        int rlc = (g << 1) + rr;
        int s = rs[rlc], e = rs[rlc + 1];
        float4 acc = make_float4(0.f, 0.f, 0.f, 0.f);
        for (int j = s; j < e; j += 8) {
            unsigned pk[8]; float vvv[8];
            #pragma unroll
            for (int k = 0; k < 8; ++k) {
                int jj = j + k;
                float2 rc = srec[jj < e ? jj : s];
                pk[k] = __float_as_uint(rc.x);
                vvv[k] = rc.y;
            }
            float4 w4[8];
            #pragma unroll
            for (int k = 0; k < 8; ++k)
                w4[k] = *(const float4*)(
                    weight + (long long)(pk[k] & CMASK) * FEAT + (l << 2));
            #pragma unroll
            for (int k = 0; k < 8; ++k) {
                float sc = (j + k < e) ? vvv[k] : 0.f;
                acc.x += sc * w4[k].x;
                acc.y += sc * w4[k].y;
                acc.z += sc * w4[k].z;
                acc.w += sc * w4[k].w;
            }
        }
        if (nspill > 0) {
            for (int i = 0; i < nspill; ++i) {
                float4 sp = spill[i];
                if ((int)__float_as_uint(sp.x) == row0 + rlc) {
                    const float4 wz = *(const float4*)(
                        weight + (long long)__float_as_uint(sp.y) * FEAT +
                        (l << 2));
                    acc.x += sp.z * wz.x;
                    acc.y += sp.z * wz.y;
                    acc.z += sp.z * wz.z;
                    acc.w += sp.z * wz.w;
                }
            }
        }
        int rrow = row0 + rlc;
        if (rrow < n_nodes) {
            float4 o = make_float4(acc.x + bf4.x, acc.y + bf4.y,
                                   acc.z + bf4.z, acc.w + bf4.w);
            *(float4*)(out + (long long)rrow * FEAT + (l << 2)) = o;
        }
    }
}

// ---------------- v2 fallback (bin + gather) ----------------

__global__ __launch_bounds__(256) void gnn_init(
    const float* __restrict__ bias, float* __restrict__ out,
    int* __restrict__ cnt, int total4, int n_nodes) {
    int i = blockIdx.x * blockDim.x + threadIdx.x;
    if (i < total4) {
        float4 bb = ((const float4*)bias)[i & 7];
        ((float4*)out)[i] = bb;
    }
    if (i < n_nodes) cnt[i] = 0;
}

__global__ __launch_bounds__(256) void gnn_bin(
    const int* __restrict__ edge_row,
    const int* __restrict__ edge_col,
    const float* __restrict__ edge_val,
    const float* __restrict__ weight,
    float2* __restrict__ bins,
    int* __restrict__ cnt,
    float* __restrict__ out,
    int num_edges, int cap) {
    int e = blockIdx.x * blockDim.x + threadIdx.x;
    if (e >= num_edges) return;
    int r = edge_row[e];
    int c = edge_col[e];
    float v = edge_val[e];
    int slot = atomicAdd(&cnt[r], 1);
    if (slot < cap) {
        bins[(long long)r * cap + slot] = make_float2(__int_as_float(c), v);
    } else {
        const float* w = weight + (long long)c * FEAT;
        #pragma unroll
        for (int f = 0; f < FEAT; ++f)
            atomicAdd(out + (long long)r * FEAT + f, v * w[f]);
    }
}

__global__ __launch_bounds__(256) void gnn_gather(
    const float2* __restrict__ bins,
    const int* __restrict__ cnt,
    const float* __restrict__ weight,
    float* __restrict__ out,
    int n_nodes, int cap) {
    int g = (blockIdx.x * blockDim.x + threadIdx.x) >> 5;
    int f = threadIdx.x & (FEAT - 1);
    if (g >= n_nodes) return;
    int n = cnt[g];
    n = n < cap ? n : cap;
    const float2* b = bins + (long long)g * cap;
    float a0 = 0.f, a1 = 0.f, a2 = 0.f, a3 = 0.f;
    int j = 0;
    for (; j + 4 <= n; j += 4) {
        float2 e0 = b[j], e1 = b[j + 1], e2 = b[j + 2], e3 = b[j + 3];
        a0 += e0.y * weight[(long long)__float_as_int(e0.x) * FEAT + f];
        a1 += e1.y * weight[(long long)__float_as_int(e1.x) * FEAT + f];
        a2 += e2.y * weight[(long long)__float_as_int(e2.x) * FEAT + f];
        a3 += e3.y * weight[(long long)__float_as_int(e3.x) * FEAT + f];
    }
    for (; j < n; ++j) {
        float2 e0 = b[j];
        a0 += e0.y * weight[(long long)__float_as_int(e0.x) * FEAT + f];
    }
    out[(long long)g * FEAT + f] += (a0 + a1) + (a2 + a3);
}

// ---------------- v0 fallback ----------------

__global__ __launch_bounds__(256) void gnn_init_out(
    const float* __restrict__ bias, float* __restrict__ out, int total) {
    int i = blockIdx.x * blockDim.x + threadIdx.x;
    if (i < total) out[i] = bias[i & (FEAT - 1)];
}

__global__ __launch_bounds__(256) void gnn_scatter(
    const int* __restrict__ edge_row,
    const int* __restrict__ edge_col,
    const float* __restrict__ edge_val,
    const float* __restrict__ weight,
    float* __restrict__ out,
    int num_edges) {
    long long t = (long long)blockIdx.x * blockDim.x + threadIdx.x;
    int e = (int)(t >> 5);
    int f = (int)(t & (FEAT - 1));
    if (e < num_edges) {
        int r = edge_row[e];
        int c = edge_col[e];
        atomicAdd(out + r * FEAT + f, edge_val[e] * weight[c * FEAT + f]);
    }
}

extern "C" void kernel_launch(void* const* d_in, const int* in_sizes, int n_in,
                              void* d_out, int out_size, void* d_ws, size_t ws_size,
                              hipStream_t stream) {
    const int*   edge_row = (const int*)d_in[0];
    const int*   edge_col = (const int*)d_in[1];
    const float* edge_val = (const float*)d_in[2];
    const float* weight   = (const float*)d_in[3];
    const float* bias     = (const float*)d_in[4];
    float* out = (float*)d_out;

    const int E = in_sizes[0];
    const int total = out_size;        // N * 32 elements
    const int N = total / FEAT;
    const int B = (N + RPB - 1) >> LOG_RPB;          // fine buckets
    const int NSB = (N + SBROWS - 1) >> LOG_SBR;     // super-buckets

    auto align256 = [](size_t x) { return (x + 255) & ~(size_t)255; };
    // ints laid contiguously for one zero kernel: cursor_sb | cursor_fine | scnt
    size_t ints = (size_t)NSB + (size_t)B + 1;
    size_t spill_off   = align256(ints * sizeof(int));
    size_t sbparts_off = align256(spill_off + (size_t)E * sizeof(float4));
    size_t parts_off   = align256(sbparts_off +
                                  (size_t)NSB * SBCAP * sizeof(float2));
    size_t need_v11    = parts_off + (size_t)B * CAPB * sizeof(float2);

    if (NSB >= 1 && NSB <= NSB_MAX && B <= BMAX && N <= (1 << COLBITS) &&
        E > 0 && ws_size >= need_v11) {
        int*    cursor_sb   = (int*)d_ws;
        int*    cursor_fine = cursor_sb + NSB;
        int*    scnt        = cursor_fine + B;
        float4* spill       = (float4*)((char*)d_ws + spill_off);
        float2* sbparts     = (float2*)((char*)d_ws + sbparts_off);
        float2* parts       = (float2*)((char*)d_ws + parts_off);

        gnn_zero<<<(int)((ints + 255) / 256), 256, 0, stream>>>(
            cursor_sb, (int)ints);
        gnn_parta<<<(E + PCHUNK - 1) / PCHUNK, PTHREADS, 0, stream>>>(
            edge_row, edge_col, edge_val, cursor_sb, sbparts, spill, scnt,
            E, NSB);
        gnn_partb<<<NSB * BCHUNKS, PTHREADS, 0, stream>>>(
            sbparts, cursor_sb, cursor_fine, parts, spill, scnt, B);
        gnn_accum<<<B, 512, 0, stream>>>(
            parts, cursor_fine, scnt, spill, weight, bias, out, N);
        return;
    }

    // v2 fallback: bin + gather
    size_t cnt_bytes = align256((size_t)N * sizeof(int));
    long long cap_ll = 0;
    if (ws_size > cnt_bytes)
        cap_ll = (long long)((ws_size - cnt_bytes) / ((size_t)N * sizeof(float2)));
    int cap = (int)(cap_ll > CAP_MAX ? CAP_MAX : cap_ll);

    if (cap >= 16) {
        int* cnt = (int*)d_ws;
        float2* bins = (float2*)((char*)d_ws + cnt_bytes);
        int total4 = total / 4;
        int init_threads = total4 > N ? total4 : N;
        gnn_init<<<(init_threads + 255) / 256, 256, 0, stream>>>(
            bias, out, cnt, total4, N);
        gnn_bin<<<(E + 255) / 256, 256, 0, stream>>>(
            edge_row, edge_col, edge_val, weight, bins, cnt, out, E, cap);
        long long gthreads = (long long)N * FEAT;
        gnn_gather<<<(int)((gthreads + 255) / 256), 256, 0, stream>>>(
            bins, cnt, weight, out, N, cap);
    } else {
        gnn_init_out<<<(total + 255) / 256, 256, 0, stream>>>(bias, out, total);
        long long threads = (long long)E * FEAT;
        gnn_scatter<<<(int)((threads + 255) / 256), 256, 0, stream>>>(
            edge_row, edge_col, edge_val, weight, out, E);
    }
}